// Round 1
// baseline (42.292 us; speedup 1.0000x reference)
//
#include <hip/hip_runtime.h>
#include <hip/hip_bf16.h>

// RandomShiftsAug on 1x1 spatial maps: out[i,:] = x[i,:] if (h1[i]==pad && w1[i]==pad) else 0.
// N = 16384 rows, C = 4096 floats/row.
//
// Memory-bound: 256 MB write is mandatory; x read is only needed for ~1/81 of
// rows (keep probability), so we branch per row and never read x for dropped
// rows. One block per row, float4 (16B/lane) stores for coalescing.

#define C_DIM 4096
#define C4 (C_DIM / 4)   // 1024 float4 per row

__global__ void __launch_bounds__(256)
random_shifts_kernel(const float* __restrict__ x,
                     const int* __restrict__ h1,
                     const int* __restrict__ w1,
                     const int* __restrict__ pad,
                     float* __restrict__ out,
                     int n_rows) {
    const int row = blockIdx.x;
    if (row >= n_rows) return;

    const int p = pad[0];
    // Wave-uniform per row: no divergence within the block.
    const bool keep = (h1[row] == p) && (w1[row] == p);

    const size_t base = (size_t)row * C_DIM;
    float4* __restrict__ orow = reinterpret_cast<float4*>(out + base);

    if (keep) {
        const float4* __restrict__ xrow = reinterpret_cast<const float4*>(x + base);
        #pragma unroll
        for (int i = threadIdx.x; i < C4; i += 256) {
            orow[i] = xrow[i];
        }
    } else {
        const float4 z = make_float4(0.f, 0.f, 0.f, 0.f);
        #pragma unroll
        for (int i = threadIdx.x; i < C4; i += 256) {
            orow[i] = z;
        }
    }
}

extern "C" void kernel_launch(void* const* d_in, const int* in_sizes, int n_in,
                              void* d_out, int out_size, void* d_ws, size_t ws_size,
                              hipStream_t stream) {
    const float* x  = (const float*)d_in[0];
    const int*   h1 = (const int*)d_in[1];
    const int*   w1 = (const int*)d_in[2];
    const int*   pad = (const int*)d_in[3];
    float* out = (float*)d_out;

    const int n_rows = in_sizes[1];  // 16384

    random_shifts_kernel<<<n_rows, 256, 0, stream>>>(x, h1, w1, pad, out, n_rows);
}